// Round 8
// baseline (268.408 us; speedup 1.0000x reference)
//
#include <hip/hip_runtime.h>
#include <math.h>

// Problem constants
#define BATCH 8
#define NNODE 512
#define BN 4096           // BATCH*NNODE
#define DIM 128
#define HID 64
#define CAP 64            // max neighbors per row (mean ~20, 10 sigma margin)

__device__ __forceinline__ float sigmoidf(float x) {
  return 1.f / (1.f + expf(-x));
}
__device__ __forceinline__ float wave_sum(float v) {
  for (int off = 1; off < 64; off <<= 1) v += __shfl_xor(v, off, 64);
  return v;
}

// ---------------------------------------------------------------------------
// GIN block (R6-proven): 8 nodes/block (2/wave), gather via padded CSR with
// 8 independent row loads in flight.  W1 staged in LDS; W2 from global (L1).
// Accumulates block column sums into Ssum[batch*320 + SOFF + col].
// smem layout: W1s[CIN*64] | aggs[8*CIN] | zs[8*64]
// ---------------------------------------------------------------------------
template <int CIN, bool MASKED, int SOFF>
__device__ __forceinline__ void gin_block(
    float* smem, int node0, const float* hin, const float* W1g,
    const float* b1, const float* W2g, const float* b2, float eps1,
    const int* csr, const int* cnt, const float* mask, float* hout,
    float* Ssum) {
  float* W1s = smem;
  float* aggs = smem + CIN * HID;
  float* zs = aggs + 8 * CIN;
  int tid = threadIdx.x, wave = tid >> 6, lane = tid & 63;
  for (int t = tid; t < CIN * HID / 4; t += 256)
    ((float4*)W1s)[t] = ((const float4*)W1g)[t];
  for (int i = 0; i < 2; i++) {
    int ln = wave * 2 + i;
    int r = node0 + ln;
    int b9 = r & ~(NNODE - 1);
    const float* hi = hin + (size_t)r * CIN;
    float a0 = eps1 * hi[lane];
    float a1 = (CIN == 128) ? eps1 * hi[lane + 64] : 0.f;
    int n = cnt[r];
    const int* nb = csr + r * CAP;
    float mrow = MASKED ? mask[r] : 1.f;
    float s0 = 0.f, s1 = 0.f;
    for (int t = 0; t < n; t += 8) {  // CSR padded to CAP: safe over-read
      int4 ja = *(const int4*)&nb[t];
      int4 jb = *(const int4*)&nb[t + 4];
      int r0 = b9 + ja.x, r1 = b9 + ja.y, r2 = b9 + ja.z, r3 = b9 + ja.w;
      int r4 = b9 + jb.x, r5 = b9 + jb.y, r6 = b9 + jb.z, r7 = b9 + jb.w;
      float m0 = MASKED ? mask[r0] : 1.f;
      float m1 = (t + 1 < n) ? (MASKED ? mask[r1] : 1.f) : 0.f;
      float m2 = (t + 2 < n) ? (MASKED ? mask[r2] : 1.f) : 0.f;
      float m3 = (t + 3 < n) ? (MASKED ? mask[r3] : 1.f) : 0.f;
      float m4 = (t + 4 < n) ? (MASKED ? mask[r4] : 1.f) : 0.f;
      float m5 = (t + 5 < n) ? (MASKED ? mask[r5] : 1.f) : 0.f;
      float m6 = (t + 6 < n) ? (MASKED ? mask[r6] : 1.f) : 0.f;
      float m7 = (t + 7 < n) ? (MASKED ? mask[r7] : 1.f) : 0.f;
      const float* p0 = hin + (size_t)r0 * CIN;
      const float* p1 = hin + (size_t)r1 * CIN;
      const float* p2 = hin + (size_t)r2 * CIN;
      const float* p3 = hin + (size_t)r3 * CIN;
      const float* p4 = hin + (size_t)r4 * CIN;
      const float* p5 = hin + (size_t)r5 * CIN;
      const float* p6 = hin + (size_t)r6 * CIN;
      const float* p7 = hin + (size_t)r7 * CIN;
      s0 += m0 * p0[lane] + m1 * p1[lane] + m2 * p2[lane] + m3 * p3[lane] +
            m4 * p4[lane] + m5 * p5[lane] + m6 * p6[lane] + m7 * p7[lane];
      if (CIN == 128)
        s1 += m0 * p0[lane + 64] + m1 * p1[lane + 64] + m2 * p2[lane + 64] +
              m3 * p3[lane + 64] + m4 * p4[lane + 64] + m5 * p5[lane + 64] +
              m6 * p6[lane + 64] + m7 * p7[lane + 64];
    }
    a0 += mrow * s0;
    if (CIN == 128) a1 += mrow * s1;
    aggs[ln * CIN + lane] = a0;
    if (CIN == 128) aggs[ln * CIN + 64 + lane] = a1;
  }
  __syncthreads();  // W1s staged, aggs written
  const float* x0 = aggs + (wave * 2 + 0) * CIN;
  const float* x1 = aggs + (wave * 2 + 1) * CIN;
  float bb = b1[lane];
  float acc0 = bb, acc1 = bb;
  for (int k = 0; k < CIN; k += 4) {
    float w0 = W1s[(k + 0) * HID + lane];
    float w1 = W1s[(k + 1) * HID + lane];
    float w2 = W1s[(k + 2) * HID + lane];
    float w3 = W1s[(k + 3) * HID + lane];
    float4 a;
    a = *(const float4*)&x0[k];
    acc0 += a.x * w0 + a.y * w1 + a.z * w2 + a.w * w3;
    a = *(const float4*)&x1[k];
    acc1 += a.x * w0 + a.y * w1 + a.z * w2 + a.w * w3;
  }
  zs[(wave * 2 + 0) * HID + lane] = fmaxf(0.f, acc0);
  zs[(wave * 2 + 1) * HID + lane] = fmaxf(0.f, acc1);
  const float* z0 = zs + (wave * 2 + 0) * HID;
  const float* z1 = zs + (wave * 2 + 1) * HID;
  float b2b = b2[lane];
  float c0 = b2b, c1v = b2b;
  for (int k = 0; k < HID; k += 4) {
    float w0 = W2g[(k + 0) * HID + lane];   // global, coalesced, L1-resident
    float w1 = W2g[(k + 1) * HID + lane];
    float w2 = W2g[(k + 2) * HID + lane];
    float w3 = W2g[(k + 3) * HID + lane];
    float4 a;
    a = *(const float4*)&z0[k];
    c0 += a.x * w0 + a.y * w1 + a.z * w2 + a.w * w3;
    a = *(const float4*)&z1[k];
    c1v += a.x * w0 + a.y * w1 + a.z * w2 + a.w * w3;
  }
  float h0 = fmaxf(0.f, c0), h1v = fmaxf(0.f, c1v);
  size_t rb = (size_t)(node0 + wave * 2) * HID + lane;
  hout[rb + 0 * HID] = h0;
  hout[rb + 1 * HID] = h1v;
  // per-block column partial -> Ssum (zs rows of this wave are dead now)
  zs[(wave * 2) * HID + lane] = h0 + h1v;
  __syncthreads();
  if (tid < HID) {
    float tot = zs[0 * HID + tid] + zs[2 * HID + tid] + zs[4 * HID + tid] +
                zs[6 * HID + tid];
    atomicAdd(&Ssum[(node0 >> 9) * 320 + SOFF + tid], tot);
  }
}

// ---------------------------------------------------------------------------
// K1 (stage 1): [0,1024): node MLPs (kappa + f0..f2), 16 nodes/block, W1 in
// LDS; [1024,2048): CSR build + degree; 2048: c1 + zero Ssum + zero done;
// [2049,2113): X column sums -> Ssum[:,0:128]  (depends only on input X).
// ---------------------------------------------------------------------------
__global__ __launch_bounds__(256) void k_stage1(
    const float* X, const float* A, const float* cW1, const float* cb1,
    const float* cW2, const float* cb2, const float* fW1, const float* fb1,
    const float* fW2, const float* fb2, const float* wm_W1, const float* wm_b1,
    const float* wm_W2, const float* wm_b2, const float* wm_W3,
    const float* wm_b3, float* kap, float* f, float* c1_out, int* csr,
    int* cnt_arr, float* deg, float* Ssum, int* done) {
  __shared__ float smem[10240];  // 40KB
  int bid = blockIdx.x;
  int tid = threadIdx.x, wave = tid >> 6, lane = tid & 63;
  if (bid < 1024) {
    int m = bid >> 8;   // which MLP: 0=kappa, 1..3=f
    int grp = bid & 255;
    float* W1s = smem;          // 8192 floats
    float* xs = smem + 8192;    // 2048 floats
    int node0 = grp * 16;
    const float* W1 = (m == 0) ? cW1 : fW1 + (size_t)(m - 1) * DIM * HID;
    for (int t = tid; t < 16 * DIM / 4; t += 256)
      ((float4*)xs)[t] = ((const float4*)(X + (size_t)node0 * DIM))[t];
    for (int t = tid; t < DIM * HID / 4; t += 256)
      ((float4*)W1s)[t] = ((const float4*)W1)[t];
    __syncthreads();
    const float* b1 = (m == 0) ? cb1 : fb1 + (m - 1) * HID;
    const float* W2 = (m == 0) ? cW2 : fW2 + (m - 1) * HID;
    float b2v = (m == 0) ? cb2[0] : fb2[m - 1];
    const float* x0 = xs + (wave * 4 + 0) * DIM;
    const float* x1 = xs + (wave * 4 + 1) * DIM;
    const float* x2 = xs + (wave * 4 + 2) * DIM;
    const float* x3 = xs + (wave * 4 + 3) * DIM;
    float w2l = W2[lane];
    float bb = b1[lane];
    float acc0 = bb, acc1 = bb, acc2 = bb, acc3 = bb;
    for (int k = 0; k < DIM; k += 4) {
      float w0 = W1s[(k + 0) * HID + lane];
      float w1 = W1s[(k + 1) * HID + lane];
      float w2 = W1s[(k + 2) * HID + lane];
      float w3 = W1s[(k + 3) * HID + lane];
      float4 a;
      a = *(const float4*)&x0[k];
      acc0 += a.x * w0 + a.y * w1 + a.z * w2 + a.w * w3;
      a = *(const float4*)&x1[k];
      acc1 += a.x * w0 + a.y * w1 + a.z * w2 + a.w * w3;
      a = *(const float4*)&x2[k];
      acc2 += a.x * w0 + a.y * w1 + a.z * w2 + a.w * w3;
      a = *(const float4*)&x3[k];
      acc3 += a.x * w0 + a.y * w1 + a.z * w2 + a.w * w3;
    }
    float s0 = wave_sum(fmaxf(0.f, acc0) * w2l);
    float s1 = wave_sum(fmaxf(0.f, acc1) * w2l);
    float s2 = wave_sum(fmaxf(0.f, acc2) * w2l);
    float s3 = wave_sum(fmaxf(0.f, acc3) * w2l);
    if (lane < 4) {
      float sv = (lane == 0) ? s0 : (lane == 1) ? s1 : (lane == 2) ? s2 : s3;
      float s = sigmoidf(sv + b2v);
      int node = node0 + wave * 4 + lane;
      if (m == 0) kap[node] = s;
      else f[node * 3 + (m - 1)] = s;
    }
    return;
  }
  if (bid < 2048) {
    int r = (bid - 1024) * 4 + wave;
    const float* row = A + (size_t)r * NNODE;
    int base = r * CAP, cnt = 0;
    for (int c = 0; c < NNODE / 64; c++) {
      int j = c * 64 + lane;
      bool nz = (row[j] != 0.f);
      unsigned long long mb = __ballot(nz);
      if (nz) {
        int pos = __popcll(mb & ((1ull << lane) - 1ull));
        int slot = cnt + pos;
        if (slot < CAP) csr[base + slot] = j;
      }
      cnt += (int)__popcll(mb);
    }
    int cc = cnt < CAP ? cnt : CAP;
    if (lane >= cc) csr[base + lane] = 0;  // pad tail for int4 over-read
    if (lane == 0) {
      cnt_arr[r] = cc;
      deg[r] = (float)cnt;
    }
    return;
  }
  if (bid == 2048) {
    // zero Ssum + done (strictly precedes all stage2-4 atomics, stream order)
    for (int t = tid; t < BATCH * 320; t += 256) Ssum[t] = 0.f;
    if (tid == 0) *done = 0;
    // c1 = scalar weight-MLP(1.0)  (weights == c1*A since A is binary)
    float* u = smem;
    float* y = smem + 64;
    int l = tid;
    if (l < 64) u[l] = fmaxf(0.f, wm_W1[l] + wm_b1[l]);
    __syncthreads();
    if (l < 32) {
      float a = wm_b2[l];
      for (int k = 0; k < 64; k++) a += u[k] * wm_W2[k * 32 + l];
      y[l] = fmaxf(0.f, a);
    }
    __syncthreads();
    if (l == 0) {
      float a = wm_b3[0];
      for (int k = 0; k < 32; k++) a += y[k] * wm_W3[k];
      *c1_out = sigmoidf(a);
    }
    return;
  }
  // X column sums: 64 blocks, each a batch-slice of 64 rows x 128 cols.
  // NOTE: these atomics race with the Ssum zeroing block only in launch
  // order within the same kernel -> must NOT overlap.  They do not: the
  // zero block (2048) writes plain stores; to be safe these use atomicAdd
  // only after the zero block ran?  Stream order can't help inside one
  // kernel, so instead: colsum blocks write their partials with atomicAdd
  // into Ssum region [0:128) which the zero block also writes.  To avoid
  // the intra-kernel race, the zero block zeroes ONLY [128:320) cols and
  // colsum blocks 0..7 (first slice of each batch) initialize [0:128) with
  // a plain store pattern: block sl==0 uses atomicExch-free init.  Simpler
  // and fully safe: colsum accumulates into SsumX (separate buffer) zeroed
  // by... to keep it simple we accumulate X sums into Ssum via atomicAdd
  // AFTER zeroing guaranteed by doing the zero in the PREVIOUS launch is
  // not available -> use dedicated buffer SsumX appended at Ssum+2560,
  // zeroed here per-block-slice with atomicExch on first slice is still
  // racy.  Resolution: each colsum block computes a FULL batch column sum
  // (8 blocks only, 64 rows x 8 slices folded in-loop) and does a PLAIN
  // STORE (one writer per element, no zero needed).
  int idx = bid - 2049;
  if (idx >= BATCH) return;      // 8 writer blocks; rest idle (grid padding)
  int b = idx;
  int col = threadIdx.x & 127, rg = threadIdx.x >> 7;  // 2 row-groups
  const float* xb = X + (size_t)b * NNODE * DIM;
  float s = 0.f;
  for (int n = rg; n < NNODE; n += 2) s += xb[(size_t)n * DIM + col];
  smem[threadIdx.x] = s;
  __syncthreads();
  if (threadIdx.x < 128) {
    // plain store: single writer per (b,col); zero block never touches [0:128)
    Ssum[b * 320 + col] = smem[threadIdx.x] + smem[threadIdx.x + 128];
  }
}

// ---------------------------------------------------------------------------
// K2 (stage 2): [0,1024): curvature pass1 + gamma terms, wave/row;
// [1024,1032): top-k rank masks; [1032,1544): GIN layer 0 (h1 colsums).
// GG[r*12]: [gamma_i, df_i, fi*df_i] i=0..2, then s1_i.
// ---------------------------------------------------------------------------
__global__ __launch_bounds__(256) void k_stage2(
    const float* X, const float* f, const float* kap, const int* p_ptr,
    const int* csr, const int* cnt, const float* deg, const float* c1p,
    const float* g0_W1, const float* g0_b1, const float* g0_W2,
    const float* g0_b2, const float* gin_eps, float* GG, float* M1, float* M2,
    float* h1, float* Ssum) {
  __shared__ float smem[9728];  // max(ks[512], gin: 128*64+8*128+8*64)
  int bid = blockIdx.x;
  int wave = threadIdx.x >> 6, lane = threadIdx.x & 63;
  if (bid < 1024) {
    int r = bid * 4 + wave;
    int b9 = r & ~(NNODE - 1);
    int n = cnt[r];
    int j = csr[r * CAP + lane];
    float f0 = 0.f, f1 = 0.f, f2 = 0.f;
    if (lane < n) {
      const float* fj = f + (size_t)(b9 + j) * 3;
      f0 = fj[0]; f1 = fj[1]; f2 = fj[2];
    }
    float s10 = wave_sum(f0), s11 = wave_sum(f1), s12 = wave_sum(f2);
    float s20 = wave_sum(f0 * f0), s21 = wave_sum(f1 * f1),
          s22 = wave_sum(f2 * f2);
    if (lane < 3) {
      float s1 = (lane == 0) ? s10 : (lane == 1) ? s11 : s12;
      float s2 = (lane == 0) ? s20 : (lane == 1) ? s21 : s22;
      float c1 = *c1p, dA = deg[r];
      float fi = f[r * 3 + lane];
      float gamma = 0.5f * c1 * (fi * fi * dA - 2.f * fi * s1 + s2);
      float df = c1 * (fi * dA - s1);
      float* o = GG + (size_t)r * 12;
      o[lane * 3 + 0] = gamma;
      o[lane * 3 + 1] = df;
      o[lane * 3 + 2] = fi * df;
      o[9 + lane] = s1;
    }
    return;
  }
  if (bid < 1024 + BATCH) {
    int b = bid - 1024;
    float* ks = smem;
    for (int t = threadIdx.x; t < NNODE; t += 256) ks[t] = kap[b * NNODE + t];
    __syncthreads();
    int p = *p_ptr;
    int num1 = (NNODE * p) / 100;
    int num2 = (NNODE * 2 * p) / 100;
    int numm = num1 > num2 ? num1 : num2;
    for (int i = threadIdx.x; i < NNODE; i += 256) {
      float v = ks[i];
      int rank = 0;
      for (int j = 0; j < NNODE; j++) {
        float u = ks[j];
        rank += (u > v) || (u == v && j < i);  // jax.lax.top_k tie-break
      }
      M1[b * NNODE + i] = (rank < num1) ? 0.f : 1.f;
      M2[b * NNODE + i] = (rank < numm) ? 0.f : 1.f;
    }
    return;
  }
  gin_block<DIM, false, 128>(smem, (bid - 1024 - BATCH) * 8, X, g0_W1, g0_b1,
                             g0_W2, g0_b2, 1.f + gin_eps[0], csr, cnt,
                             nullptr, h1, Ssum);
}

// ---------------------------------------------------------------------------
// K3 (stage 3): [0,1024): curvature pass2 -> loss_part[bid];
// [1024,1536): GIN layer 1 (mask M1; h2 colsums -> Ssum[:,192:256]).
// ---------------------------------------------------------------------------
__global__ __launch_bounds__(256) void k_stage3(
    const float* f, const float* kap, const float* deg, const float* GG,
    const int* csr, const int* cnt, const float* c1p, float* loss_part,
    const float* h1, const float* g1_W1, const float* g1_b1,
    const float* g1_W2, const float* g1_b2, const float* gin_eps,
    const float* M1, float* h2, float* Ssum) {
  __shared__ float smem[5120];  // GIN branch: 64*64+8*64+8*64
  __shared__ float part[4];
  int bid = blockIdx.x;
  int wave = threadIdx.x >> 6, lane = threadIdx.x & 63;
  if (bid < 1024) {
    int r = bid * 4 + wave;
    int b9 = r & ~(NNODE - 1);
    int n = cnt[r];
    int j = csr[r * CAP + lane];
    float T[9];
    for (int c = 0; c < 9; c++) T[c] = 0.f;
    if (lane < n) {
      const float4* g = (const float4*)(GG + (size_t)(b9 + j) * 12);
      float4 g0 = g[0], g1 = g[1], g2 = g[2];
      T[0] = g0.x; T[1] = g0.y; T[2] = g0.z;
      T[3] = g0.w; T[4] = g1.x; T[5] = g1.y;
      T[6] = g1.z; T[7] = g1.w; T[8] = g2.x;
    }
    for (int c = 0; c < 9; c++) T[c] = wave_sum(T[c]);
    float kp = kap[r];
    float local = 0.f;
    if (lane < 3) {
      int i = lane;
      float c1 = *c1p, dA = deg[r];
      const float* o = GG + (size_t)r * 12;
      float fi = f[r * 3 + i];
      float s1 = o[9 + i];
      float gamma = o[i * 3 + 0], df = o[i * 3 + 1];
      float dgamma = c1 * (gamma * dA - T[i * 3 + 0]);
      float gfd = 0.5f * c1 * (fi * df * dA - fi * T[i * 3 + 1] - df * s1 +
                               T[i * 3 + 2]);
      float gamma2 = 0.5f * dgamma - gfd;
      local = fmaxf(0.f, kp * gamma - gamma2);
    }
    if (lane == 0) local -= 3.f * kp;  // "- kappa.sum()" once per f_i
    local = wave_sum(local);
    if (lane == 0) part[wave] = local;
    __syncthreads();
    if (threadIdx.x == 0)
      loss_part[bid] = part[0] + part[1] + part[2] + part[3];
    return;
  }
  gin_block<HID, true, 192>(smem, (bid - 1024) * 8, h1, g1_W1, g1_b1, g1_W2,
                            g1_b2, 1.f + gin_eps[1], csr, cnt, M1, h2, Ssum);
}

// ---------------------------------------------------------------------------
// K4 (stage 4): GIN layer 2 (mask M2 == M1*M2 by top-k nesting; h3 colsums
// -> Ssum[:,256:320]).  The LAST block to finish (atomic done-counter) then
// performs the readout: out[b] = Ssum[b] @ out_W + out_b, out[80] = loss.
// Ssum is read back with atomicAdd(p, 0.f) to get L2-coherent values
// (same-kernel cross-block visibility; loss_part is from a prior launch so
// plain loads are fine).
// ---------------------------------------------------------------------------
__global__ __launch_bounds__(256) void k_stage4(
    const float* h2, const float* g2_W1, const float* g2_b1,
    const float* g2_W2, const float* g2_b2, const float* gin_eps,
    const int* csr, const int* cnt, const float* M2, float* h3, float* Ssum,
    int* done, const float* loss_part, const float* out_W, const float* out_b,
    float* out) {
  __shared__ float smem[5120];
  __shared__ int is_last;
  gin_block<HID, true, 256>(smem, blockIdx.x * 8, h2, g2_W1, g2_b1, g2_W2,
                            g2_b2, 1.f + gin_eps[2], csr, cnt, M2, h3, Ssum);
  __syncthreads();
  if (threadIdx.x == 0) {
    __threadfence();                       // drain this block's Ssum atomics
    is_last = (atomicAdd(done, 1) == gridDim.x - 1);
  }
  __syncthreads();
  if (!is_last) return;
  // ---- readout by the final block (all other blocks' atomics visible) ----
  int t = threadIdx.x;
  float* S = smem;  // 2560 floats
  for (int i = t; i < BATCH * 320; i += 256)
    S[i] = atomicAdd(&Ssum[i], 0.f);       // L2-coherent read
  // loss: 1024 partials from stage3 (prior launch)
  float ls = 0.f;
  for (int i = t; i < 1024; i += 256) ls += loss_part[i];
  ls = wave_sum(ls);
  if ((t & 63) == 0) smem[2560 + (t >> 6)] = ls;
  __syncthreads();
  if (t < 80) {
    int b = t / 10, oc = t % 10;
    float acc = out_b[oc];
    const float* Sb = S + b * 320;
    for (int d = 0; d < 320; d++) acc += Sb[d] * out_W[d * 10 + oc];
    out[b * 10 + oc] = acc;
  }
  if (t == 0)
    out[80] = smem[2560] + smem[2561] + smem[2562] + smem[2563];
}

// ---------------------------------------------------------------------------
extern "C" void kernel_launch(void* const* d_in, const int* in_sizes, int n_in,
                              void* d_out, int out_size, void* d_ws,
                              size_t ws_size, hipStream_t stream) {
  const float* X       = (const float*)d_in[0];
  const float* A       = (const float*)d_in[1];
  const int*   p       = (const int*)d_in[2];
  const float* curv_W1 = (const float*)d_in[3];
  const float* curv_b1 = (const float*)d_in[4];
  const float* curv_W2 = (const float*)d_in[5];
  const float* curv_b2 = (const float*)d_in[6];
  const float* wm_W1   = (const float*)d_in[7];
  const float* wm_b1   = (const float*)d_in[8];
  const float* wm_W2   = (const float*)d_in[9];
  const float* wm_b2   = (const float*)d_in[10];
  const float* wm_W3   = (const float*)d_in[11];
  const float* wm_b3   = (const float*)d_in[12];
  const float* fn_W1   = (const float*)d_in[13];
  const float* fn_b1   = (const float*)d_in[14];
  const float* fn_W2   = (const float*)d_in[15];
  const float* fn_b2   = (const float*)d_in[16];
  const float* gin_eps = (const float*)d_in[17];
  const float* g0_W1   = (const float*)d_in[18];
  const float* g0_b1   = (const float*)d_in[19];
  const float* g0_W2   = (const float*)d_in[20];
  const float* g0_b2   = (const float*)d_in[21];
  const float* g1_W1   = (const float*)d_in[22];
  const float* g1_b1   = (const float*)d_in[23];
  const float* g1_W2   = (const float*)d_in[24];
  const float* g1_b2   = (const float*)d_in[25];
  const float* g2_W1   = (const float*)d_in[26];
  const float* g2_b1   = (const float*)d_in[27];
  const float* g2_W2   = (const float*)d_in[28];
  const float* g2_b2   = (const float*)d_in[29];
  const float* out_W   = (const float*)d_in[30];
  const float* out_b   = (const float*)d_in[31];
  float* out = (float*)d_out;

  float* ws = (float*)d_ws;
  size_t o = 0;
  float* loss_part = ws + o; o += 1024;
  float* c1       = ws + o; o += 16;
  float* Ssum     = ws + o; o += BATCH * 320 + 16;
  float* kap      = ws + o; o += BN;
  float* f        = ws + o; o += (size_t)BN * 3 + 16;
  float* deg      = ws + o; o += BN;
  float* M1       = ws + o; o += BN;
  float* M2       = ws + o; o += BN;
  float* GG       = ws + o; o += (size_t)BN * 12;
  float* h1       = ws + o; o += (size_t)BN * HID;
  float* h2       = ws + o; o += (size_t)BN * HID;
  float* h3       = ws + o; o += (size_t)BN * HID;
  int* cnt  = (int*)(ws + o); o += BN;
  int* done = (int*)(ws + o); o += 16;
  int* csr  = (int*)(ws + o); o += (size_t)BN * CAP;

  k_stage1<<<2049 + BATCH, 256, 0, stream>>>(
      X, A, curv_W1, curv_b1, curv_W2, curv_b2, fn_W1, fn_b1, fn_W2, fn_b2,
      wm_W1, wm_b1, wm_W2, wm_b2, wm_W3, wm_b3, kap, f, c1, csr, cnt, deg,
      Ssum, done);
  k_stage2<<<1024 + BATCH + 512, 256, 0, stream>>>(
      X, f, kap, p, csr, cnt, deg, c1, g0_W1, g0_b1, g0_W2, g0_b2, gin_eps,
      GG, M1, M2, h1, Ssum);
  k_stage3<<<1536, 256, 0, stream>>>(f, kap, deg, GG, csr, cnt, c1, loss_part,
                                     h1, g1_W1, g1_b1, g1_W2, g1_b2, gin_eps,
                                     M1, h2, Ssum);
  k_stage4<<<512, 256, 0, stream>>>(h2, g2_W1, g2_b1, g2_W2, g2_b2, gin_eps,
                                    csr, cnt, M2, h3, Ssum, done, loss_part,
                                    out_W, out_b, out);
}

// Round 9
// 239.969 us; speedup vs baseline: 1.1185x; 1.1185x over previous
//
#include <hip/hip_runtime.h>
#include <math.h>

// Problem constants
#define BATCH 8
#define NNODE 512
#define BN 4096           // BATCH*NNODE
#define DIM 128
#define HID 64
#define CAP 64            // max neighbors per row (mean ~20, 10 sigma margin)

__device__ __forceinline__ float sigmoidf(float x) {
  return 1.f / (1.f + expf(-x));
}
__device__ __forceinline__ float wave_sum(float v) {
  for (int off = 1; off < 64; off <<= 1) v += __shfl_xor(v, off, 64);
  return v;
}

// ---------------------------------------------------------------------------
// GIN block (R6-proven): 8 nodes/block (2/wave), gather via padded CSR with
// 8 independent row loads in flight.  W1 staged in LDS; W2 from global (L1).
// Accumulates block column sums into Ssum[batch*320 + SOFF + col].
// smem layout: W1s[CIN*64] | aggs[8*CIN] | zs[8*64]
// ---------------------------------------------------------------------------
template <int CIN, bool MASKED, int SOFF>
__device__ __forceinline__ void gin_block(
    float* smem, int node0, const float* hin, const float* W1g,
    const float* b1, const float* W2g, const float* b2, float eps1,
    const int* csr, const int* cnt, const float* mask, float* hout,
    float* Ssum) {
  float* W1s = smem;
  float* aggs = smem + CIN * HID;
  float* zs = aggs + 8 * CIN;
  int tid = threadIdx.x, wave = tid >> 6, lane = tid & 63;
  for (int t = tid; t < CIN * HID / 4; t += 256)
    ((float4*)W1s)[t] = ((const float4*)W1g)[t];
  for (int i = 0; i < 2; i++) {
    int ln = wave * 2 + i;
    int r = node0 + ln;
    int b9 = r & ~(NNODE - 1);
    const float* hi = hin + (size_t)r * CIN;
    float a0 = eps1 * hi[lane];
    float a1 = (CIN == 128) ? eps1 * hi[lane + 64] : 0.f;
    int n = cnt[r];
    const int* nb = csr + r * CAP;
    float mrow = MASKED ? mask[r] : 1.f;
    float s0 = 0.f, s1 = 0.f;
    for (int t = 0; t < n; t += 8) {  // CSR padded to CAP: safe over-read
      int4 ja = *(const int4*)&nb[t];
      int4 jb = *(const int4*)&nb[t + 4];
      int r0 = b9 + ja.x, r1 = b9 + ja.y, r2 = b9 + ja.z, r3 = b9 + ja.w;
      int r4 = b9 + jb.x, r5 = b9 + jb.y, r6 = b9 + jb.z, r7 = b9 + jb.w;
      float m0 = MASKED ? mask[r0] : 1.f;
      float m1 = (t + 1 < n) ? (MASKED ? mask[r1] : 1.f) : 0.f;
      float m2 = (t + 2 < n) ? (MASKED ? mask[r2] : 1.f) : 0.f;
      float m3 = (t + 3 < n) ? (MASKED ? mask[r3] : 1.f) : 0.f;
      float m4 = (t + 4 < n) ? (MASKED ? mask[r4] : 1.f) : 0.f;
      float m5 = (t + 5 < n) ? (MASKED ? mask[r5] : 1.f) : 0.f;
      float m6 = (t + 6 < n) ? (MASKED ? mask[r6] : 1.f) : 0.f;
      float m7 = (t + 7 < n) ? (MASKED ? mask[r7] : 1.f) : 0.f;
      const float* p0 = hin + (size_t)r0 * CIN;
      const float* p1 = hin + (size_t)r1 * CIN;
      const float* p2 = hin + (size_t)r2 * CIN;
      const float* p3 = hin + (size_t)r3 * CIN;
      const float* p4 = hin + (size_t)r4 * CIN;
      const float* p5 = hin + (size_t)r5 * CIN;
      const float* p6 = hin + (size_t)r6 * CIN;
      const float* p7 = hin + (size_t)r7 * CIN;
      s0 += m0 * p0[lane] + m1 * p1[lane] + m2 * p2[lane] + m3 * p3[lane] +
            m4 * p4[lane] + m5 * p5[lane] + m6 * p6[lane] + m7 * p7[lane];
      if (CIN == 128)
        s1 += m0 * p0[lane + 64] + m1 * p1[lane + 64] + m2 * p2[lane + 64] +
              m3 * p3[lane + 64] + m4 * p4[lane + 64] + m5 * p5[lane + 64] +
              m6 * p6[lane + 64] + m7 * p7[lane + 64];
    }
    a0 += mrow * s0;
    if (CIN == 128) a1 += mrow * s1;
    aggs[ln * CIN + lane] = a0;
    if (CIN == 128) aggs[ln * CIN + 64 + lane] = a1;
  }
  __syncthreads();  // W1s staged, aggs written
  const float* x0 = aggs + (wave * 2 + 0) * CIN;
  const float* x1 = aggs + (wave * 2 + 1) * CIN;
  float bb = b1[lane];
  float acc0 = bb, acc1 = bb;
  for (int k = 0; k < CIN; k += 4) {
    float w0 = W1s[(k + 0) * HID + lane];
    float w1 = W1s[(k + 1) * HID + lane];
    float w2 = W1s[(k + 2) * HID + lane];
    float w3 = W1s[(k + 3) * HID + lane];
    float4 a;
    a = *(const float4*)&x0[k];
    acc0 += a.x * w0 + a.y * w1 + a.z * w2 + a.w * w3;
    a = *(const float4*)&x1[k];
    acc1 += a.x * w0 + a.y * w1 + a.z * w2 + a.w * w3;
  }
  zs[(wave * 2 + 0) * HID + lane] = fmaxf(0.f, acc0);
  zs[(wave * 2 + 1) * HID + lane] = fmaxf(0.f, acc1);
  const float* z0 = zs + (wave * 2 + 0) * HID;
  const float* z1 = zs + (wave * 2 + 1) * HID;
  float b2b = b2[lane];
  float c0 = b2b, c1v = b2b;
  for (int k = 0; k < HID; k += 4) {
    float w0 = W2g[(k + 0) * HID + lane];   // global, coalesced, L1-resident
    float w1 = W2g[(k + 1) * HID + lane];
    float w2 = W2g[(k + 2) * HID + lane];
    float w3 = W2g[(k + 3) * HID + lane];
    float4 a;
    a = *(const float4*)&z0[k];
    c0 += a.x * w0 + a.y * w1 + a.z * w2 + a.w * w3;
    a = *(const float4*)&z1[k];
    c1v += a.x * w0 + a.y * w1 + a.z * w2 + a.w * w3;
  }
  float h0 = fmaxf(0.f, c0), h1v = fmaxf(0.f, c1v);
  size_t rb = (size_t)(node0 + wave * 2) * HID + lane;
  hout[rb + 0 * HID] = h0;
  hout[rb + 1 * HID] = h1v;
  // per-block column partial -> Ssum (zs rows of this wave are dead now)
  zs[(wave * 2) * HID + lane] = h0 + h1v;
  __syncthreads();
  if (tid < HID) {
    float tot = zs[0 * HID + tid] + zs[2 * HID + tid] + zs[4 * HID + tid] +
                zs[6 * HID + tid];
    atomicAdd(&Ssum[(node0 >> 9) * 320 + SOFF + tid], tot);
  }
}

// ---------------------------------------------------------------------------
// K1 (stage 1): blocks [0,1024): node MLPs (kappa + f0..f2), 16 nodes/block,
// W1 in LDS; [1024,2048): CSR build + degree; 2048: c1 + zero Ssum + done.
// ---------------------------------------------------------------------------
__global__ __launch_bounds__(256) void k_stage1(
    const float* X, const float* A, const float* cW1, const float* cb1,
    const float* cW2, const float* cb2, const float* fW1, const float* fb1,
    const float* fW2, const float* fb2, const float* wm_W1, const float* wm_b1,
    const float* wm_W2, const float* wm_b2, const float* wm_W3,
    const float* wm_b3, float* kap, float* f, float* c1_out, int* csr,
    int* cnt_arr, float* deg, float* Ssum, int* done) {
  __shared__ float smem[10240];  // 40KB
  int bid = blockIdx.x;
  int tid = threadIdx.x, wave = tid >> 6, lane = tid & 63;
  if (bid < 1024) {
    int m = bid >> 8;   // which MLP: 0=kappa, 1..3=f
    int grp = bid & 255;
    float* W1s = smem;          // 8192 floats
    float* xs = smem + 8192;    // 2048 floats
    int node0 = grp * 16;
    const float* W1 = (m == 0) ? cW1 : fW1 + (size_t)(m - 1) * DIM * HID;
    for (int t = tid; t < 16 * DIM / 4; t += 256)
      ((float4*)xs)[t] = ((const float4*)(X + (size_t)node0 * DIM))[t];
    for (int t = tid; t < DIM * HID / 4; t += 256)
      ((float4*)W1s)[t] = ((const float4*)W1)[t];
    __syncthreads();
    const float* b1 = (m == 0) ? cb1 : fb1 + (m - 1) * HID;
    const float* W2 = (m == 0) ? cW2 : fW2 + (m - 1) * HID;
    float b2v = (m == 0) ? cb2[0] : fb2[m - 1];
    const float* x0 = xs + (wave * 4 + 0) * DIM;
    const float* x1 = xs + (wave * 4 + 1) * DIM;
    const float* x2 = xs + (wave * 4 + 2) * DIM;
    const float* x3 = xs + (wave * 4 + 3) * DIM;
    float w2l = W2[lane];
    float bb = b1[lane];
    float acc0 = bb, acc1 = bb, acc2 = bb, acc3 = bb;
    for (int k = 0; k < DIM; k += 4) {
      float w0 = W1s[(k + 0) * HID + lane];
      float w1 = W1s[(k + 1) * HID + lane];
      float w2 = W1s[(k + 2) * HID + lane];
      float w3 = W1s[(k + 3) * HID + lane];
      float4 a;
      a = *(const float4*)&x0[k];
      acc0 += a.x * w0 + a.y * w1 + a.z * w2 + a.w * w3;
      a = *(const float4*)&x1[k];
      acc1 += a.x * w0 + a.y * w1 + a.z * w2 + a.w * w3;
      a = *(const float4*)&x2[k];
      acc2 += a.x * w0 + a.y * w1 + a.z * w2 + a.w * w3;
      a = *(const float4*)&x3[k];
      acc3 += a.x * w0 + a.y * w1 + a.z * w2 + a.w * w3;
    }
    float s0 = wave_sum(fmaxf(0.f, acc0) * w2l);
    float s1 = wave_sum(fmaxf(0.f, acc1) * w2l);
    float s2 = wave_sum(fmaxf(0.f, acc2) * w2l);
    float s3 = wave_sum(fmaxf(0.f, acc3) * w2l);
    if (lane < 4) {
      float sv = (lane == 0) ? s0 : (lane == 1) ? s1 : (lane == 2) ? s2 : s3;
      float s = sigmoidf(sv + b2v);
      int node = node0 + wave * 4 + lane;
      if (m == 0) kap[node] = s;
      else f[node * 3 + (m - 1)] = s;
    }
    return;
  }
  if (bid < 2048) {
    int r = (bid - 1024) * 4 + wave;
    const float* row = A + (size_t)r * NNODE;
    int base = r * CAP, cnt = 0;
    for (int c = 0; c < NNODE / 64; c++) {
      int j = c * 64 + lane;
      bool nz = (row[j] != 0.f);
      unsigned long long mb = __ballot(nz);
      if (nz) {
        int pos = __popcll(mb & ((1ull << lane) - 1ull));
        int slot = cnt + pos;
        if (slot < CAP) csr[base + slot] = j;
      }
      cnt += (int)__popcll(mb);
    }
    int cc = cnt < CAP ? cnt : CAP;
    if (lane >= cc) csr[base + lane] = 0;  // pad tail for int4 over-read
    if (lane == 0) {
      cnt_arr[r] = cc;
      deg[r] = (float)cnt;
    }
    return;
  }
  // zero Ssum + done (strictly precedes all stage2-4 atomics, stream order)
  for (int t = tid; t < BATCH * 320; t += 256) Ssum[t] = 0.f;
  if (tid == 0) *done = 0;
  // c1 = scalar weight-MLP(1.0)  (weights == c1*A since A is binary)
  float* u = smem;
  float* y = smem + 64;
  int l = tid;
  if (l < 64) u[l] = fmaxf(0.f, wm_W1[l] + wm_b1[l]);
  __syncthreads();
  if (l < 32) {
    float a = wm_b2[l];
    for (int k = 0; k < 64; k++) a += u[k] * wm_W2[k * 32 + l];
    y[l] = fmaxf(0.f, a);
  }
  __syncthreads();
  if (l == 0) {
    float a = wm_b3[0];
    for (int k = 0; k < 32; k++) a += y[k] * wm_W3[k];
    *c1_out = sigmoidf(a);
  }
}

// ---------------------------------------------------------------------------
// K2 (stage 2): [0,1024): curvature pass1 + gamma terms, wave/row;
// [1024,1032): top-k rank masks; [1032,1544): GIN layer 0 (h1 colsums);
// [1544,1608): X column sums -> Ssum[:,0:128] via atomicAdd (Ssum zeroed in
// stage1 -> stream-ordered, safe).
// GG[r*12]: [gamma_i, df_i, fi*df_i] i=0..2, then s1_i.
// ---------------------------------------------------------------------------
__global__ __launch_bounds__(256) void k_stage2(
    const float* X, const float* f, const float* kap, const int* p_ptr,
    const int* csr, const int* cnt, const float* deg, const float* c1p,
    const float* g0_W1, const float* g0_b1, const float* g0_W2,
    const float* g0_b2, const float* gin_eps, float* GG, float* M1, float* M2,
    float* h1, float* Ssum) {
  __shared__ float smem[9728];  // max(ks[512], gin: 128*64+8*128+8*64)
  int bid = blockIdx.x;
  int wave = threadIdx.x >> 6, lane = threadIdx.x & 63;
  if (bid < 1024) {
    int r = bid * 4 + wave;
    int b9 = r & ~(NNODE - 1);
    int n = cnt[r];
    int j = csr[r * CAP + lane];
    float f0 = 0.f, f1 = 0.f, f2 = 0.f;
    if (lane < n) {
      const float* fj = f + (size_t)(b9 + j) * 3;
      f0 = fj[0]; f1 = fj[1]; f2 = fj[2];
    }
    float s10 = wave_sum(f0), s11 = wave_sum(f1), s12 = wave_sum(f2);
    float s20 = wave_sum(f0 * f0), s21 = wave_sum(f1 * f1),
          s22 = wave_sum(f2 * f2);
    if (lane < 3) {
      float s1 = (lane == 0) ? s10 : (lane == 1) ? s11 : s12;
      float s2 = (lane == 0) ? s20 : (lane == 1) ? s21 : s22;
      float c1 = *c1p, dA = deg[r];
      float fi = f[r * 3 + lane];
      float gamma = 0.5f * c1 * (fi * fi * dA - 2.f * fi * s1 + s2);
      float df = c1 * (fi * dA - s1);
      float* o = GG + (size_t)r * 12;
      o[lane * 3 + 0] = gamma;
      o[lane * 3 + 1] = df;
      o[lane * 3 + 2] = fi * df;
      o[9 + lane] = s1;
    }
    return;
  }
  if (bid < 1024 + BATCH) {
    int b = bid - 1024;
    float* ks = smem;
    for (int t = threadIdx.x; t < NNODE; t += 256) ks[t] = kap[b * NNODE + t];
    __syncthreads();
    int p = *p_ptr;
    int num1 = (NNODE * p) / 100;
    int num2 = (NNODE * 2 * p) / 100;
    int numm = num1 > num2 ? num1 : num2;
    for (int i = threadIdx.x; i < NNODE; i += 256) {
      float v = ks[i];
      int rank = 0;
      for (int j = 0; j < NNODE; j++) {
        float u = ks[j];
        rank += (u > v) || (u == v && j < i);  // jax.lax.top_k tie-break
      }
      M1[b * NNODE + i] = (rank < num1) ? 0.f : 1.f;
      M2[b * NNODE + i] = (rank < numm) ? 0.f : 1.f;
    }
    return;
  }
  if (bid < 1024 + BATCH + 512) {
    gin_block<DIM, false, 128>(smem, (bid - 1024 - BATCH) * 8, X, g0_W1,
                               g0_b1, g0_W2, g0_b2, 1.f + gin_eps[0], csr,
                               cnt, nullptr, h1, Ssum);
    return;
  }
  // X column sums: 64 blocks, each a batch-slice of 64 rows x 128 cols
  int idx = bid - (1024 + BATCH + 512);
  int b = idx >> 3, sl = idx & 7;
  int col = threadIdx.x & 127, rg = threadIdx.x >> 7;  // 2 row-groups
  const float* xb = X + (size_t)b * NNODE * DIM;
  int n0 = sl * 64;
  float s = 0.f;
  for (int n = n0 + rg; n < n0 + 64; n += 2) s += xb[(size_t)n * DIM + col];
  smem[threadIdx.x] = s;
  __syncthreads();
  if (threadIdx.x < 128)
    atomicAdd(&Ssum[b * 320 + col], smem[threadIdx.x] + smem[threadIdx.x + 128]);
}

// ---------------------------------------------------------------------------
// K3 (stage 3): [0,1024): curvature pass2 -> loss_part[bid];
// [1024,1536): GIN layer 1 (mask M1; h2 colsums -> Ssum[:,192:256]).
// ---------------------------------------------------------------------------
__global__ __launch_bounds__(256) void k_stage3(
    const float* f, const float* kap, const float* deg, const float* GG,
    const int* csr, const int* cnt, const float* c1p, float* loss_part,
    const float* h1, const float* g1_W1, const float* g1_b1,
    const float* g1_W2, const float* g1_b2, const float* gin_eps,
    const float* M1, float* h2, float* Ssum) {
  __shared__ float smem[5120];  // GIN branch: 64*64+8*64+8*64
  __shared__ float part[4];
  int bid = blockIdx.x;
  int wave = threadIdx.x >> 6, lane = threadIdx.x & 63;
  if (bid < 1024) {
    int r = bid * 4 + wave;
    int b9 = r & ~(NNODE - 1);
    int n = cnt[r];
    int j = csr[r * CAP + lane];
    float T[9];
    for (int c = 0; c < 9; c++) T[c] = 0.f;
    if (lane < n) {
      const float4* g = (const float4*)(GG + (size_t)(b9 + j) * 12);
      float4 g0 = g[0], g1 = g[1], g2 = g[2];
      T[0] = g0.x; T[1] = g0.y; T[2] = g0.z;
      T[3] = g0.w; T[4] = g1.x; T[5] = g1.y;
      T[6] = g1.z; T[7] = g1.w; T[8] = g2.x;
    }
    for (int c = 0; c < 9; c++) T[c] = wave_sum(T[c]);
    float kp = kap[r];
    float local = 0.f;
    if (lane < 3) {
      int i = lane;
      float c1 = *c1p, dA = deg[r];
      const float* o = GG + (size_t)r * 12;
      float fi = f[r * 3 + i];
      float s1 = o[9 + i];
      float gamma = o[i * 3 + 0], df = o[i * 3 + 1];
      float dgamma = c1 * (gamma * dA - T[i * 3 + 0]);
      float gfd = 0.5f * c1 * (fi * df * dA - fi * T[i * 3 + 1] - df * s1 +
                               T[i * 3 + 2]);
      float gamma2 = 0.5f * dgamma - gfd;
      local = fmaxf(0.f, kp * gamma - gamma2);
    }
    if (lane == 0) local -= 3.f * kp;  // "- kappa.sum()" once per f_i
    local = wave_sum(local);
    if (lane == 0) part[wave] = local;
    __syncthreads();
    if (threadIdx.x == 0)
      loss_part[bid] = part[0] + part[1] + part[2] + part[3];
    return;
  }
  gin_block<HID, true, 192>(smem, (bid - 1024) * 8, h1, g1_W1, g1_b1, g1_W2,
                            g1_b2, 1.f + gin_eps[1], csr, cnt, M1, h2, Ssum);
}

// ---------------------------------------------------------------------------
// K4 (stage 4): GIN layer 2 (mask M2 == M1*M2 by top-k nesting; h3 colsums
// -> Ssum[:,256:320]).  Last block (atomic done-counter; ALL threads fence
// before the count) performs the readout GEMM + loss reduction.
// ---------------------------------------------------------------------------
__global__ __launch_bounds__(256) void k_stage4(
    const float* h2, const float* g2_W1, const float* g2_b1,
    const float* g2_W2, const float* g2_b2, const float* gin_eps,
    const int* csr, const int* cnt, const float* M2, float* h3, float* Ssum,
    int* done, const float* loss_part, const float* out_W, const float* out_b,
    float* out) {
  __shared__ float smem[5126];
  __shared__ int is_last;
  gin_block<HID, true, 256>(smem, blockIdx.x * 8, h2, g2_W1, g2_b1, g2_W2,
                            g2_b2, 1.f + gin_eps[2], csr, cnt, M2, h3, Ssum);
  __threadfence();   // every thread drains its own Ssum atomics
  __syncthreads();
  if (threadIdx.x == 0)
    is_last = (atomicAdd(done, 1) == (int)gridDim.x - 1);
  __syncthreads();
  if (!is_last) return;
  // ---- readout by the final block (all other blocks' atomics visible) ----
  int t = threadIdx.x;
  float* S = smem;  // 2560 floats (reuses gin scratch; block is past it)
  for (int i = t; i < BATCH * 320; i += 256)
    S[i] = atomicAdd(&Ssum[i], 0.f);       // L2-coherent read
  float ls = 0.f;
  for (int i = t; i < 1024; i += 256) ls += loss_part[i];  // prior launch
  ls = wave_sum(ls);
  if ((t & 63) == 0) smem[2560 + (t >> 6)] = ls;
  __syncthreads();
  if (t < 80) {
    int b = t / 10, oc = t % 10;
    float acc = out_b[oc];
    const float* Sb = S + b * 320;
    for (int d = 0; d < 320; d++) acc += Sb[d] * out_W[d * 10 + oc];
    out[b * 10 + oc] = acc;
  }
  if (t == 0)
    out[80] = smem[2560] + smem[2561] + smem[2562] + smem[2563];
}

// ---------------------------------------------------------------------------
extern "C" void kernel_launch(void* const* d_in, const int* in_sizes, int n_in,
                              void* d_out, int out_size, void* d_ws,
                              size_t ws_size, hipStream_t stream) {
  const float* X       = (const float*)d_in[0];
  const float* A       = (const float*)d_in[1];
  const int*   p       = (const int*)d_in[2];
  const float* curv_W1 = (const float*)d_in[3];
  const float* curv_b1 = (const float*)d_in[4];
  const float* curv_W2 = (const float*)d_in[5];
  const float* curv_b2 = (const float*)d_in[6];
  const float* wm_W1   = (const float*)d_in[7];
  const float* wm_b1   = (const float*)d_in[8];
  const float* wm_W2   = (const float*)d_in[9];
  const float* wm_b2   = (const float*)d_in[10];
  const float* wm_W3   = (const float*)d_in[11];
  const float* wm_b3   = (const float*)d_in[12];
  const float* fn_W1   = (const float*)d_in[13];
  const float* fn_b1   = (const float*)d_in[14];
  const float* fn_W2   = (const float*)d_in[15];
  const float* fn_b2   = (const float*)d_in[16];
  const float* gin_eps = (const float*)d_in[17];
  const float* g0_W1   = (const float*)d_in[18];
  const float* g0_b1   = (const float*)d_in[19];
  const float* g0_W2   = (const float*)d_in[20];
  const float* g0_b2   = (const float*)d_in[21];
  const float* g1_W1   = (const float*)d_in[22];
  const float* g1_b1   = (const float*)d_in[23];
  const float* g1_W2   = (const float*)d_in[24];
  const float* g1_b2   = (const float*)d_in[25];
  const float* g2_W1   = (const float*)d_in[26];
  const float* g2_b1   = (const float*)d_in[27];
  const float* g2_W2   = (const float*)d_in[28];
  const float* g2_b2   = (const float*)d_in[29];
  const float* out_W   = (const float*)d_in[30];
  const float* out_b   = (const float*)d_in[31];
  float* out = (float*)d_out;

  float* ws = (float*)d_ws;
  size_t o = 0;
  float* loss_part = ws + o; o += 1024;
  float* c1       = ws + o; o += 16;
  float* Ssum     = ws + o; o += BATCH * 320 + 16;
  float* kap      = ws + o; o += BN;
  float* f        = ws + o; o += (size_t)BN * 3 + 16;
  float* deg      = ws + o; o += BN;
  float* M1       = ws + o; o += BN;
  float* M2       = ws + o; o += BN;
  float* GG       = ws + o; o += (size_t)BN * 12;
  float* h1       = ws + o; o += (size_t)BN * HID;
  float* h2       = ws + o; o += (size_t)BN * HID;
  float* h3       = ws + o; o += (size_t)BN * HID;
  int* cnt  = (int*)(ws + o); o += BN;
  int* done = (int*)(ws + o); o += 16;
  int* csr  = (int*)(ws + o); o += (size_t)BN * CAP;

  k_stage1<<<2049, 256, 0, stream>>>(
      X, A, curv_W1, curv_b1, curv_W2, curv_b2, fn_W1, fn_b1, fn_W2, fn_b2,
      wm_W1, wm_b1, wm_W2, wm_b2, wm_W3, wm_b3, kap, f, c1, csr, cnt, deg,
      Ssum, done);
  k_stage2<<<1024 + BATCH + 512 + 64, 256, 0, stream>>>(
      X, f, kap, p, csr, cnt, deg, c1, g0_W1, g0_b1, g0_W2, g0_b2, gin_eps,
      GG, M1, M2, h1, Ssum);
  k_stage3<<<1536, 256, 0, stream>>>(f, kap, deg, GG, csr, cnt, c1, loss_part,
                                     h1, g1_W1, g1_b1, g1_W2, g1_b2, gin_eps,
                                     M1, h2, Ssum);
  k_stage4<<<512, 256, 0, stream>>>(h2, g2_W1, g2_b1, g2_W2, g2_b2, gin_eps,
                                    csr, cnt, M2, h3, Ssum, done, loss_part,
                                    out_W, out_b, out);
}

// Round 10
// 199.387 us; speedup vs baseline: 1.3462x; 1.2035x over previous
//
#include <hip/hip_runtime.h>
#include <math.h>

// Problem constants
#define BATCH 8
#define NNODE 512
#define BN 4096           // BATCH*NNODE
#define DIM 128
#define HID 64
#define CAP 64            // max neighbors per row (mean ~20, 10 sigma margin)

__device__ __forceinline__ float sigmoidf(float x) {
  return 1.f / (1.f + expf(-x));
}
__device__ __forceinline__ float wave_sum(float v) {
  for (int off = 1; off < 64; off <<= 1) v += __shfl_xor(v, off, 64);
  return v;
}

// ---------------------------------------------------------------------------
// GIN block (R6-proven): 8 nodes/block (2/wave), gather via padded CSR with
// 8 independent row loads in flight.  W1 staged in LDS; W2 from global (L1).
// Accumulates block column sums into Ssum[batch*320 + SOFF + col].
// smem layout: W1s[CIN*64] | aggs[8*CIN] | zs[8*64]
// ---------------------------------------------------------------------------
template <int CIN, bool MASKED, int SOFF>
__device__ __forceinline__ void gin_block(
    float* smem, int node0, const float* hin, const float* W1g,
    const float* b1, const float* W2g, const float* b2, float eps1,
    const int* csr, const int* cnt, const float* mask, float* hout,
    float* Ssum) {
  float* W1s = smem;
  float* aggs = smem + CIN * HID;
  float* zs = aggs + 8 * CIN;
  int tid = threadIdx.x, wave = tid >> 6, lane = tid & 63;
  for (int t = tid; t < CIN * HID / 4; t += 256)
    ((float4*)W1s)[t] = ((const float4*)W1g)[t];
  for (int i = 0; i < 2; i++) {
    int ln = wave * 2 + i;
    int r = node0 + ln;
    int b9 = r & ~(NNODE - 1);
    const float* hi = hin + (size_t)r * CIN;
    float a0 = eps1 * hi[lane];
    float a1 = (CIN == 128) ? eps1 * hi[lane + 64] : 0.f;
    int n = cnt[r];
    const int* nb = csr + r * CAP;
    float mrow = MASKED ? mask[r] : 1.f;
    float s0 = 0.f, s1 = 0.f;
    for (int t = 0; t < n; t += 8) {  // CSR padded to CAP: safe over-read
      int4 ja = *(const int4*)&nb[t];
      int4 jb = *(const int4*)&nb[t + 4];
      int r0 = b9 + ja.x, r1 = b9 + ja.y, r2 = b9 + ja.z, r3 = b9 + ja.w;
      int r4 = b9 + jb.x, r5 = b9 + jb.y, r6 = b9 + jb.z, r7 = b9 + jb.w;
      float m0 = MASKED ? mask[r0] : 1.f;
      float m1 = (t + 1 < n) ? (MASKED ? mask[r1] : 1.f) : 0.f;
      float m2 = (t + 2 < n) ? (MASKED ? mask[r2] : 1.f) : 0.f;
      float m3 = (t + 3 < n) ? (MASKED ? mask[r3] : 1.f) : 0.f;
      float m4 = (t + 4 < n) ? (MASKED ? mask[r4] : 1.f) : 0.f;
      float m5 = (t + 5 < n) ? (MASKED ? mask[r5] : 1.f) : 0.f;
      float m6 = (t + 6 < n) ? (MASKED ? mask[r6] : 1.f) : 0.f;
      float m7 = (t + 7 < n) ? (MASKED ? mask[r7] : 1.f) : 0.f;
      const float* p0 = hin + (size_t)r0 * CIN;
      const float* p1 = hin + (size_t)r1 * CIN;
      const float* p2 = hin + (size_t)r2 * CIN;
      const float* p3 = hin + (size_t)r3 * CIN;
      const float* p4 = hin + (size_t)r4 * CIN;
      const float* p5 = hin + (size_t)r5 * CIN;
      const float* p6 = hin + (size_t)r6 * CIN;
      const float* p7 = hin + (size_t)r7 * CIN;
      s0 += m0 * p0[lane] + m1 * p1[lane] + m2 * p2[lane] + m3 * p3[lane] +
            m4 * p4[lane] + m5 * p5[lane] + m6 * p6[lane] + m7 * p7[lane];
      if (CIN == 128)
        s1 += m0 * p0[lane + 64] + m1 * p1[lane + 64] + m2 * p2[lane + 64] +
              m3 * p3[lane + 64] + m4 * p4[lane + 64] + m5 * p5[lane + 64] +
              m6 * p6[lane + 64] + m7 * p7[lane + 64];
    }
    a0 += mrow * s0;
    if (CIN == 128) a1 += mrow * s1;
    aggs[ln * CIN + lane] = a0;
    if (CIN == 128) aggs[ln * CIN + 64 + lane] = a1;
  }
  __syncthreads();  // W1s staged, aggs written
  const float* x0 = aggs + (wave * 2 + 0) * CIN;
  const float* x1 = aggs + (wave * 2 + 1) * CIN;
  float bb = b1[lane];
  float acc0 = bb, acc1 = bb;
  for (int k = 0; k < CIN; k += 4) {
    float w0 = W1s[(k + 0) * HID + lane];
    float w1 = W1s[(k + 1) * HID + lane];
    float w2 = W1s[(k + 2) * HID + lane];
    float w3 = W1s[(k + 3) * HID + lane];
    float4 a;
    a = *(const float4*)&x0[k];
    acc0 += a.x * w0 + a.y * w1 + a.z * w2 + a.w * w3;
    a = *(const float4*)&x1[k];
    acc1 += a.x * w0 + a.y * w1 + a.z * w2 + a.w * w3;
  }
  zs[(wave * 2 + 0) * HID + lane] = fmaxf(0.f, acc0);
  zs[(wave * 2 + 1) * HID + lane] = fmaxf(0.f, acc1);
  const float* z0 = zs + (wave * 2 + 0) * HID;
  const float* z1 = zs + (wave * 2 + 1) * HID;
  float b2b = b2[lane];
  float c0 = b2b, c1v = b2b;
  for (int k = 0; k < HID; k += 4) {
    float w0 = W2g[(k + 0) * HID + lane];   // global, coalesced, L1-resident
    float w1 = W2g[(k + 1) * HID + lane];
    float w2 = W2g[(k + 2) * HID + lane];
    float w3 = W2g[(k + 3) * HID + lane];
    float4 a;
    a = *(const float4*)&z0[k];
    c0 += a.x * w0 + a.y * w1 + a.z * w2 + a.w * w3;
    a = *(const float4*)&z1[k];
    c1v += a.x * w0 + a.y * w1 + a.z * w2 + a.w * w3;
  }
  float h0 = fmaxf(0.f, c0), h1v = fmaxf(0.f, c1v);
  size_t rb = (size_t)(node0 + wave * 2) * HID + lane;
  hout[rb + 0 * HID] = h0;
  hout[rb + 1 * HID] = h1v;
  // per-block column partial -> Ssum (zs rows of this wave are dead now)
  zs[(wave * 2) * HID + lane] = h0 + h1v;
  __syncthreads();
  if (tid < HID) {
    float tot = zs[0 * HID + tid] + zs[2 * HID + tid] + zs[4 * HID + tid] +
                zs[6 * HID + tid];
    atomicAdd(&Ssum[(node0 >> 9) * 320 + SOFF + tid], tot);
  }
}

// ---------------------------------------------------------------------------
// K1 (stage 1): blocks [0,1024): node MLPs (kappa + f0..f2), 16 nodes/block,
// W1 in LDS; [1024,2048): CSR build + degree; 2048: c1 + zero Ssum.
// ---------------------------------------------------------------------------
__global__ __launch_bounds__(256) void k_stage1(
    const float* X, const float* A, const float* cW1, const float* cb1,
    const float* cW2, const float* cb2, const float* fW1, const float* fb1,
    const float* fW2, const float* fb2, const float* wm_W1, const float* wm_b1,
    const float* wm_W2, const float* wm_b2, const float* wm_W3,
    const float* wm_b3, float* kap, float* f, float* c1_out, int* csr,
    int* cnt_arr, float* deg, float* Ssum) {
  __shared__ float smem[10240];  // 40KB
  int bid = blockIdx.x;
  int tid = threadIdx.x, wave = tid >> 6, lane = tid & 63;
  if (bid < 1024) {
    int m = bid >> 8;   // which MLP: 0=kappa, 1..3=f
    int grp = bid & 255;
    float* W1s = smem;          // 8192 floats
    float* xs = smem + 8192;    // 2048 floats
    int node0 = grp * 16;
    const float* W1 = (m == 0) ? cW1 : fW1 + (size_t)(m - 1) * DIM * HID;
    for (int t = tid; t < 16 * DIM / 4; t += 256)
      ((float4*)xs)[t] = ((const float4*)(X + (size_t)node0 * DIM))[t];
    for (int t = tid; t < DIM * HID / 4; t += 256)
      ((float4*)W1s)[t] = ((const float4*)W1)[t];
    __syncthreads();
    const float* b1 = (m == 0) ? cb1 : fb1 + (m - 1) * HID;
    const float* W2 = (m == 0) ? cW2 : fW2 + (m - 1) * HID;
    float b2v = (m == 0) ? cb2[0] : fb2[m - 1];
    const float* x0 = xs + (wave * 4 + 0) * DIM;
    const float* x1 = xs + (wave * 4 + 1) * DIM;
    const float* x2 = xs + (wave * 4 + 2) * DIM;
    const float* x3 = xs + (wave * 4 + 3) * DIM;
    float w2l = W2[lane];
    float bb = b1[lane];
    float acc0 = bb, acc1 = bb, acc2 = bb, acc3 = bb;
    for (int k = 0; k < DIM; k += 4) {
      float w0 = W1s[(k + 0) * HID + lane];
      float w1 = W1s[(k + 1) * HID + lane];
      float w2 = W1s[(k + 2) * HID + lane];
      float w3 = W1s[(k + 3) * HID + lane];
      float4 a;
      a = *(const float4*)&x0[k];
      acc0 += a.x * w0 + a.y * w1 + a.z * w2 + a.w * w3;
      a = *(const float4*)&x1[k];
      acc1 += a.x * w0 + a.y * w1 + a.z * w2 + a.w * w3;
      a = *(const float4*)&x2[k];
      acc2 += a.x * w0 + a.y * w1 + a.z * w2 + a.w * w3;
      a = *(const float4*)&x3[k];
      acc3 += a.x * w0 + a.y * w1 + a.z * w2 + a.w * w3;
    }
    float s0 = wave_sum(fmaxf(0.f, acc0) * w2l);
    float s1 = wave_sum(fmaxf(0.f, acc1) * w2l);
    float s2 = wave_sum(fmaxf(0.f, acc2) * w2l);
    float s3 = wave_sum(fmaxf(0.f, acc3) * w2l);
    if (lane < 4) {
      float sv = (lane == 0) ? s0 : (lane == 1) ? s1 : (lane == 2) ? s2 : s3;
      float s = sigmoidf(sv + b2v);
      int node = node0 + wave * 4 + lane;
      if (m == 0) kap[node] = s;
      else f[node * 3 + (m - 1)] = s;
    }
    return;
  }
  if (bid < 2048) {
    int r = (bid - 1024) * 4 + wave;
    const float* row = A + (size_t)r * NNODE;
    int base = r * CAP, cnt = 0;
    for (int c = 0; c < NNODE / 64; c++) {
      int j = c * 64 + lane;
      bool nz = (row[j] != 0.f);
      unsigned long long mb = __ballot(nz);
      if (nz) {
        int pos = __popcll(mb & ((1ull << lane) - 1ull));
        int slot = cnt + pos;
        if (slot < CAP) csr[base + slot] = j;
      }
      cnt += (int)__popcll(mb);
    }
    int cc = cnt < CAP ? cnt : CAP;
    if (lane >= cc) csr[base + lane] = 0;  // pad tail for int4 over-read
    if (lane == 0) {
      cnt_arr[r] = cc;
      deg[r] = (float)cnt;
    }
    return;
  }
  // zero Ssum (strictly precedes all stage2-4 atomics, stream order)
  for (int t = tid; t < BATCH * 320; t += 256) Ssum[t] = 0.f;
  // c1 = scalar weight-MLP(1.0)  (weights == c1*A since A is binary)
  float* u = smem;
  float* y = smem + 64;
  int l = tid;
  if (l < 64) u[l] = fmaxf(0.f, wm_W1[l] + wm_b1[l]);
  __syncthreads();
  if (l < 32) {
    float a = wm_b2[l];
    for (int k = 0; k < 64; k++) a += u[k] * wm_W2[k * 32 + l];
    y[l] = fmaxf(0.f, a);
  }
  __syncthreads();
  if (l == 0) {
    float a = wm_b3[0];
    for (int k = 0; k < 32; k++) a += y[k] * wm_W3[k];
    *c1_out = sigmoidf(a);
  }
}

// ---------------------------------------------------------------------------
// K2 (stage 2): [0,8): fused curvature pass1+pass2+loss, one block per
// batch, all per-node terms (gamma, df, f*df, s1) in LDS, one barrier
// between the two graph hops -> loss_part[b];
// [8,16): top-k rank masks; [16,528): GIN layer 0 (h1 colsums);
// [528,592): X column sums -> Ssum[:,0:128] via atomicAdd.
// ---------------------------------------------------------------------------
__global__ __launch_bounds__(256) void k_stage2(
    const float* X, const float* f, const float* kap, const int* p_ptr,
    const int* csr, const int* cnt, const float* deg, const float* c1p,
    const float* g0_W1, const float* g0_b1, const float* g0_W2,
    const float* g0_b2, const float* gin_eps, float* loss_part, float* M1,
    float* M2, float* h1, float* Ssum) {
  __shared__ float smem[9728];  // gin: 128*64+8*128+8*64; curv: 7680+4
  int bid = blockIdx.x;
  int tid = threadIdx.x;
  int wave = tid >> 6, lane = tid & 63;
  if (bid < BATCH) {
    // ---- fused curvature: batch b, 512 rows, 2 rows/thread ----
    int b = bid;
    float* fv = smem;            // 512*3
    float* ggv = smem + 1536;    // 512*9: [gamma,df,f*df] x3
    float* s1v = smem + 6144;    // 512*3
    float* part = smem + 7680;   // 4
    for (int t = tid; t < NNODE * 3; t += 256)
      fv[t] = f[b * NNODE * 3 + t];
    __syncthreads();
    float c1 = *c1p;
    // phase 1: per-row neighbor f sums -> gamma/df terms in LDS
    for (int rr = 0; rr < 2; rr++) {
      int r = tid * 2 + rr;
      int gr = b * NNODE + r;
      int n = cnt[gr];
      const int* nb = csr + gr * CAP;
      float s1[3] = {0, 0, 0}, s2[3] = {0, 0, 0};
      for (int t = 0; t < n; t += 4) {   // csr padded: safe over-read
        int4 j4 = *(const int4*)&nb[t];
        float w1 = (t + 1 < n) ? 1.f : 0.f;
        float w2 = (t + 2 < n) ? 1.f : 0.f;
        float w3 = (t + 3 < n) ? 1.f : 0.f;
        const float* p0 = &fv[j4.x * 3];
        const float* p1 = &fv[j4.y * 3];
        const float* p2 = &fv[j4.z * 3];
        const float* p3 = &fv[j4.w * 3];
        for (int i = 0; i < 3; i++) {
          float v0 = p0[i], v1 = p1[i], v2 = p2[i], v3 = p3[i];
          s1[i] += v0 + w1 * v1 + w2 * v2 + w3 * v3;
          s2[i] += v0 * v0 + w1 * v1 * v1 + w2 * v2 * v2 + w3 * v3 * v3;
        }
      }
      float dA = deg[gr];
      for (int i = 0; i < 3; i++) {
        float fi = fv[r * 3 + i];
        float gamma = 0.5f * c1 * (fi * fi * dA - 2.f * fi * s1[i] + s2[i]);
        float df = c1 * (fi * dA - s1[i]);
        ggv[r * 9 + i * 3 + 0] = gamma;
        ggv[r * 9 + i * 3 + 1] = df;
        ggv[r * 9 + i * 3 + 2] = fi * df;
        s1v[r * 3 + i] = s1[i];
      }
    }
    __syncthreads();
    // phase 2: neighbor sums of [gamma,df,f*df] -> loss
    float local = 0.f;
    for (int rr = 0; rr < 2; rr++) {
      int r = tid * 2 + rr;
      int gr = b * NNODE + r;
      int n = cnt[gr];
      const int* nb = csr + gr * CAP;
      float T[9];
      for (int c = 0; c < 9; c++) T[c] = 0.f;
      for (int t = 0; t < n; t += 4) {
        int4 j4 = *(const int4*)&nb[t];
        float w1 = (t + 1 < n) ? 1.f : 0.f;
        float w2 = (t + 2 < n) ? 1.f : 0.f;
        float w3 = (t + 3 < n) ? 1.f : 0.f;
        const float* g0 = &ggv[j4.x * 9];
        const float* g1 = &ggv[j4.y * 9];
        const float* g2 = &ggv[j4.z * 9];
        const float* g3 = &ggv[j4.w * 9];
        for (int c = 0; c < 9; c++)
          T[c] += g0[c] + w1 * g1[c] + w2 * g2[c] + w3 * g3[c];
      }
      float dA = deg[gr];
      float kp = kap[gr];
      for (int i = 0; i < 3; i++) {
        float fi = fv[r * 3 + i];
        float s1 = s1v[r * 3 + i];
        float gamma = ggv[r * 9 + i * 3 + 0];
        float df = ggv[r * 9 + i * 3 + 1];
        float dgamma = c1 * (gamma * dA - T[i * 3 + 0]);
        float gfd = 0.5f * c1 * (fi * df * dA - fi * T[i * 3 + 1] -
                                 df * s1 + T[i * 3 + 2]);
        float gamma2 = 0.5f * dgamma - gfd;
        local += fmaxf(0.f, kp * gamma - gamma2);
      }
      local -= 3.f * kp;   // "- kappa.sum()" once per f_i, per node
    }
    local = wave_sum(local);
    if (lane == 0) part[wave] = local;
    __syncthreads();
    if (tid == 0) loss_part[b] = part[0] + part[1] + part[2] + part[3];
    return;
  }
  if (bid < 2 * BATCH) {
    int b = bid - BATCH;
    float* ks = smem;
    for (int t = tid; t < NNODE; t += 256) ks[t] = kap[b * NNODE + t];
    __syncthreads();
    int p = *p_ptr;
    int num1 = (NNODE * p) / 100;
    int num2 = (NNODE * 2 * p) / 100;
    int numm = num1 > num2 ? num1 : num2;
    for (int i = tid; i < NNODE; i += 256) {
      float v = ks[i];
      int rank = 0;
      for (int j = 0; j < NNODE; j++) {
        float u = ks[j];
        rank += (u > v) || (u == v && j < i);  // jax.lax.top_k tie-break
      }
      M1[b * NNODE + i] = (rank < num1) ? 0.f : 1.f;
      M2[b * NNODE + i] = (rank < numm) ? 0.f : 1.f;
    }
    return;
  }
  if (bid < 2 * BATCH + 512) {
    gin_block<DIM, false, 128>(smem, (bid - 2 * BATCH) * 8, X, g0_W1, g0_b1,
                               g0_W2, g0_b2, 1.f + gin_eps[0], csr, cnt,
                               nullptr, h1, Ssum);
    return;
  }
  // X column sums: 64 blocks, each a batch-slice of 64 rows x 128 cols
  int idx = bid - (2 * BATCH + 512);
  int b = idx >> 3, sl = idx & 7;
  int col = tid & 127, rg = tid >> 7;  // 2 row-groups
  const float* xb = X + (size_t)b * NNODE * DIM;
  int n0 = sl * 64;
  float s = 0.f;
  for (int n = n0 + rg; n < n0 + 64; n += 2) s += xb[(size_t)n * DIM + col];
  smem[tid] = s;
  __syncthreads();
  if (tid < 128)
    atomicAdd(&Ssum[b * 320 + col], smem[tid] + smem[tid + 128]);
}

// ---------------------------------------------------------------------------
// K3 (stage 3): GIN layer 1 only (mask M1; h2 colsums -> Ssum[:,192:256]).
// ---------------------------------------------------------------------------
__global__ __launch_bounds__(256) void k_stage3(
    const float* h1, const float* g1_W1, const float* g1_b1,
    const float* g1_W2, const float* g1_b2, const float* gin_eps,
    const int* csr, const int* cnt, const float* M1, float* h2, float* Ssum) {
  __shared__ float smem[5120];  // 64*64+8*64+8*64
  gin_block<HID, true, 192>(smem, blockIdx.x * 8, h1, g1_W1, g1_b1, g1_W2,
                            g1_b2, 1.f + gin_eps[1], csr, cnt, M1, h2, Ssum);
}

// ---------------------------------------------------------------------------
// K4 (stage 4): GIN layer 2 (mask M2 == M1*M2 by top-k nesting; h3 colsums
// -> Ssum[:,256:320]).
// ---------------------------------------------------------------------------
__global__ __launch_bounds__(256) void k_stage4(
    const float* h2, const float* g2_W1, const float* g2_b1,
    const float* g2_W2, const float* g2_b2, const float* gin_eps,
    const int* csr, const int* cnt, const float* M2, float* h3, float* Ssum) {
  __shared__ float smem[5120];
  gin_block<HID, true, 256>(smem, blockIdx.x * 8, h2, g2_W1, g2_b1, g2_W2,
                            g2_b2, 1.f + gin_eps[2], csr, cnt, M2, h3, Ssum);
}

// ---------------------------------------------------------------------------
// K5: tiny readout: out[b] = Ssum[b] @ out_W + out_b; loss from 8 partials.
// ---------------------------------------------------------------------------
__global__ __launch_bounds__(320) void k_out(
    const float* Ssum, const float* out_W, const float* out_b,
    const float* loss_part, float* out) {
  int b = blockIdx.x;
  int t = threadIdx.x;  // 320
  __shared__ float S[320];
  S[t] = Ssum[b * 320 + t];
  __syncthreads();
  if (t < 10) {
    float acc = out_b[t];
    for (int d = 0; d < 320; d++) acc += S[d] * out_W[d * 10 + t];
    out[b * 10 + t] = acc;
  }
  if (b == 0 && t == 0) {
    float ls = 0.f;
    for (int i = 0; i < BATCH; i++) ls += loss_part[i];
    out[80] = ls;
  }
}

// ---------------------------------------------------------------------------
extern "C" void kernel_launch(void* const* d_in, const int* in_sizes, int n_in,
                              void* d_out, int out_size, void* d_ws,
                              size_t ws_size, hipStream_t stream) {
  const float* X       = (const float*)d_in[0];
  const float* A       = (const float*)d_in[1];
  const int*   p       = (const int*)d_in[2];
  const float* curv_W1 = (const float*)d_in[3];
  const float* curv_b1 = (const float*)d_in[4];
  const float* curv_W2 = (const float*)d_in[5];
  const float* curv_b2 = (const float*)d_in[6];
  const float* wm_W1   = (const float*)d_in[7];
  const float* wm_b1   = (const float*)d_in[8];
  const float* wm_W2   = (const float*)d_in[9];
  const float* wm_b2   = (const float*)d_in[10];
  const float* wm_W3   = (const float*)d_in[11];
  const float* wm_b3   = (const float*)d_in[12];
  const float* fn_W1   = (const float*)d_in[13];
  const float* fn_b1   = (const float*)d_in[14];
  const float* fn_W2   = (const float*)d_in[15];
  const float* fn_b2   = (const float*)d_in[16];
  const float* gin_eps = (const float*)d_in[17];
  const float* g0_W1   = (const float*)d_in[18];
  const float* g0_b1   = (const float*)d_in[19];
  const float* g0_W2   = (const float*)d_in[20];
  const float* g0_b2   = (const float*)d_in[21];
  const float* g1_W1   = (const float*)d_in[22];
  const float* g1_b1   = (const float*)d_in[23];
  const float* g1_W2   = (const float*)d_in[24];
  const float* g1_b2   = (const float*)d_in[25];
  const float* g2_W1   = (const float*)d_in[26];
  const float* g2_b1   = (const float*)d_in[27];
  const float* g2_W2   = (const float*)d_in[28];
  const float* g2_b2   = (const float*)d_in[29];
  const float* out_W   = (const float*)d_in[30];
  const float* out_b   = (const float*)d_in[31];
  float* out = (float*)d_out;

  float* ws = (float*)d_ws;
  size_t o = 0;
  float* loss_part = ws + o; o += 16;
  float* c1       = ws + o; o += 16;
  float* Ssum     = ws + o; o += BATCH * 320 + 16;
  float* kap      = ws + o; o += BN;
  float* f        = ws + o; o += (size_t)BN * 3 + 16;
  float* deg      = ws + o; o += BN;
  float* M1       = ws + o; o += BN;
  float* M2       = ws + o; o += BN;
  float* h1       = ws + o; o += (size_t)BN * HID;
  float* h2       = ws + o; o += (size_t)BN * HID;
  float* h3       = ws + o; o += (size_t)BN * HID;
  int* cnt  = (int*)(ws + o); o += BN;
  int* csr  = (int*)(ws + o); o += (size_t)BN * CAP;

  k_stage1<<<2049, 256, 0, stream>>>(
      X, A, curv_W1, curv_b1, curv_W2, curv_b2, fn_W1, fn_b1, fn_W2, fn_b2,
      wm_W1, wm_b1, wm_W2, wm_b2, wm_W3, wm_b3, kap, f, c1, csr, cnt, deg,
      Ssum);
  k_stage2<<<2 * BATCH + 512 + 64, 256, 0, stream>>>(
      X, f, kap, p, csr, cnt, deg, c1, g0_W1, g0_b1, g0_W2, g0_b2, gin_eps,
      loss_part, M1, M2, h1, Ssum);
  k_stage3<<<512, 256, 0, stream>>>(h1, g1_W1, g1_b1, g1_W2, g1_b2, gin_eps,
                                    csr, cnt, M1, h2, Ssum);
  k_stage4<<<512, 256, 0, stream>>>(h2, g2_W1, g2_b1, g2_W2, g2_b2, gin_eps,
                                    csr, cnt, M2, h3, Ssum);
  k_out<<<BATCH, 320, 0, stream>>>(Ssum, out_W, out_b, loss_part, out);
}